// Round 3
// baseline (115.844 us; speedup 1.0000x reference)
//
#include <hip/hip_runtime.h>

#define NGAUSS 2048
#define NPIX   65536
#define WID    512.0f
#define HEI    512.0f
#define NSLICE 16                 // N-dimension split for occupancy
#define GPB    (NGAUSS / NSLICE)  // 128 gaussians per block
#define NPG    128                // pixel groups (NPIX / 512)
#define PPT    2                  // pixels per thread (packed float2 lanes)

typedef float v2f __attribute__((ext_vector_type(2)));

// Per-gaussian record in d_ws: 9 duplicated float2 coefficients (72 B):
// {A,A}{B,B}{C,C}{D,D}{E0,E0}{E1,E1}{r,r}{g,g}{b,b}
// dx = A*X + B*Y + E0 ; dy = C*X + D*Y + E1 ; w = exp2(-(dx^2+dy^2))
// A..E pre-scaled by sqrt(log2(e)) so exp(-q) == exp2(-q_scaled).
// Duplication lets them load as 64-bit SGPR pairs feeding v_pk_fma_f32
// directly (one scalar operand per VALU instr — gfx950 constraint).

__global__ __launch_bounds__(256) void prep_kernel(
    const float* __restrict__ rgb, const float* __restrict__ mu,
    const float* __restrict__ scale, const float* __restrict__ angle,
    v2f* __restrict__ P)
{
    int n = blockIdx.x * blockDim.x + threadIdx.x;
    if (n >= NGAUSS) return;
    const float MU_BORDER = 1.05f;
    const float S_MIN = 1.0f / 30.0f;
    const float S_MAX = 1.0f / 0.75f;
    const float PI_APPROX = 3.1416f;
    const float K = 1.2011224087864498f;  // sqrt(log2(e))

    float mx = tanhf(mu[2*n+0]) * MU_BORDER * (0.5f * WID);
    float my = tanhf(mu[2*n+1]) * MU_BORDER * (0.5f * HEI);
    float al = tanhf(angle[n]) * PI_APPROX;
    float c = cosf(al);
    float s = sinf(al);
    float S0 = 1.0f / (1.0f + expf(-scale[2*n+0])) * (S_MAX - S_MIN) + S_MIN;
    float S1 = 1.0f / (1.0f + expf(-scale[2*n+1])) * (S_MAX - S_MIN) + S_MIN;

    float A  =  S0 * c * K;
    float Bc = -(S0 * s * K);
    float C  =  S1 * s * K;
    float D  =  S1 * c * K;
    float E0 = -(A * mx + Bc * my);
    float E1 = -(C * mx + D  * my);

    float r = 1.0f / (1.0f + expf(-rgb[3*n+0]));
    float g = 1.0f / (1.0f + expf(-rgb[3*n+1]));
    float b = 1.0f / (1.0f + expf(-rgb[3*n+2]));

    v2f* p = P + (size_t)n * 9;
    p[0] = (v2f){A, A};   p[1] = (v2f){Bc, Bc};
    p[2] = (v2f){C, C};   p[3] = (v2f){D, D};
    p[4] = (v2f){E0, E0}; p[5] = (v2f){E1, E1};
    p[6] = (v2f){r, r};   p[7] = (v2f){g, g};
    p[8] = (v2f){b, b};
}

__global__ __launch_bounds__(256) void splat_kernel(
    const float2* __restrict__ x, const v2f* __restrict__ P,
    float* __restrict__ out)
{
    // block = (slice, pixel-group). Same-pg slices are 128 blockIdx apart
    // -> same XCD under %8 round-robin -> atomic lines stay in one L2.
    const int pg    = blockIdx.x & (NPG - 1);
    const int slice = blockIdx.x >> 7;
    const int tid   = threadIdx.x;

    const int p0 = pg * 512 + tid;        // pixel 0 (lane-coalesced)
    const int p1 = p0 + 256;              // pixel 1
    float2 xy0 = x[p0];
    float2 xy1 = x[p1];
    v2f PX = {xy0.x - 0.5f * WID, xy1.x - 0.5f * WID};
    v2f PY = {xy0.y - 0.5f * HEI, xy1.y - 0.5f * HEI};

    v2f ar = {0.f, 0.f}, ag = {0.f, 0.f}, ab = {0.f, 0.f};

    const v2f* __restrict__ G = P + (size_t)(slice * GPB) * 9;
    #pragma unroll 2
    for (int j = 0; j < GPB; ++j) {
        const v2f* g = G + (size_t)j * 9;   // uniform address -> s_load
        v2f A  = g[0];
        v2f Bc = g[1];
        v2f C  = g[2];
        v2f D  = g[3];
        v2f E0 = g[4];
        v2f E1 = g[5];
        v2f dx = __builtin_elementwise_fma(A, PX,
                   __builtin_elementwise_fma(Bc, PY, E0));
        v2f dy = __builtin_elementwise_fma(C, PX,
                   __builtin_elementwise_fma(D, PY, E1));
        v2f q  = __builtin_elementwise_fma(dx, dx, dy * dy);
        v2f w;
        w.x = __builtin_amdgcn_exp2f(-q.x);
        w.y = __builtin_amdgcn_exp2f(-q.y);
        ar = __builtin_elementwise_fma(w, g[6], ar);
        ag = __builtin_elementwise_fma(w, g[7], ag);
        ab = __builtin_elementwise_fma(w, g[8], ab);
    }

    atomicAdd(&out[3*p0 + 0], ar.x);
    atomicAdd(&out[3*p0 + 1], ag.x);
    atomicAdd(&out[3*p0 + 2], ab.x);
    atomicAdd(&out[3*p1 + 0], ar.y);
    atomicAdd(&out[3*p1 + 1], ag.y);
    atomicAdd(&out[3*p1 + 2], ab.y);
}

extern "C" void kernel_launch(void* const* d_in, const int* in_sizes, int n_in,
                              void* d_out, int out_size, void* d_ws, size_t ws_size,
                              hipStream_t stream) {
    const float* x     = (const float*)d_in[0];  // [B,2]
    const float* rgb   = (const float*)d_in[1];  // [N,3]
    const float* mu    = (const float*)d_in[2];  // [N,2]
    const float* scale = (const float*)d_in[3];  // [N,2]
    const float* angle = (const float*)d_in[4];  // [N]
    v2f* P = (v2f*)d_ws;                         // 2048*72B = 147 KiB

    hipMemsetAsync(d_out, 0, (size_t)out_size * sizeof(float), stream);

    hipLaunchKernelGGL(prep_kernel, dim3(NGAUSS / 256), dim3(256), 0, stream,
                       rgb, mu, scale, angle, P);
    hipLaunchKernelGGL(splat_kernel, dim3(NSLICE * NPG), dim3(256), 0, stream,
                       (const float2*)x, P, (float*)d_out);
}

// Round 4
// 104.674 us; speedup vs baseline: 1.1067x; 1.1067x over previous
//
#include <hip/hip_runtime.h>

#define NGAUSS 2048
#define NPIX   65536
#define WID    512.0f
#define HEI    512.0f
#define NSLICE 16                 // gaussian split across blocks
#define GPB    (NGAUSS / NSLICE)  // 128 gaussians per block
#define TPB    1024               // threads per block
#define PPB    2048               // pixels per block (2 per thread, packed)
#define NPG    (NPIX / PPB)       // 32 pixel groups

typedef float v2f __attribute__((ext_vector_type(2)));

// Per-gaussian record (pre-duplicated for packed math):
//   Pmain[4n+0] = (A,A,B,B)  Pmain[4n+1] = (C,C,D,D)
//   Pmain[4n+2] = (E0,E0,E1,E1)  Pmain[4n+3] = (r,r,g,g)   Pbb[n] = (b,b)
// dx = A*X + B*Y + E0 ; dy = C*X + D*Y + E1 ; w = exp2(-(dx^2+dy^2))
// A..E pre-scaled by sqrt(log2(e)). Duplication means every packed operand
// is a register-pair alias of a ds_read_b128 result — zero splat movs.

static __device__ __forceinline__ v2f lo2(float4 v) { return (v2f){v.x, v.y}; }
static __device__ __forceinline__ v2f hi2(float4 v) { return (v2f){v.z, v.w}; }

__global__ __launch_bounds__(256) void prep_kernel(
    const float* __restrict__ rgb, const float* __restrict__ mu,
    const float* __restrict__ scale, const float* __restrict__ angle,
    float4* __restrict__ Pmain, float2* __restrict__ Pbb)
{
    int n = blockIdx.x * blockDim.x + threadIdx.x;
    if (n >= NGAUSS) return;
    const float MU_BORDER = 1.05f;
    const float S_MIN = 1.0f / 30.0f;
    const float S_MAX = 1.0f / 0.75f;
    const float PI_APPROX = 3.1416f;
    const float K = 1.2011224087864498f;  // sqrt(log2(e))

    float mx = tanhf(mu[2*n+0]) * MU_BORDER * (0.5f * WID);
    float my = tanhf(mu[2*n+1]) * MU_BORDER * (0.5f * HEI);
    float al = tanhf(angle[n]) * PI_APPROX;
    float c = cosf(al);
    float s = sinf(al);
    float S0 = 1.0f / (1.0f + expf(-scale[2*n+0])) * (S_MAX - S_MIN) + S_MIN;
    float S1 = 1.0f / (1.0f + expf(-scale[2*n+1])) * (S_MAX - S_MIN) + S_MIN;

    float A  =  S0 * c * K;
    float Bc = -(S0 * s * K);
    float C  =  S1 * s * K;
    float D  =  S1 * c * K;
    float E0 = -(A * mx + Bc * my);
    float E1 = -(C * mx + D  * my);

    float r = 1.0f / (1.0f + expf(-rgb[3*n+0]));
    float g = 1.0f / (1.0f + expf(-rgb[3*n+1]));
    float b = 1.0f / (1.0f + expf(-rgb[3*n+2]));

    float4* p = Pmain + 4*n;
    p[0] = make_float4(A, A, Bc, Bc);
    p[1] = make_float4(C, C, D, D);
    p[2] = make_float4(E0, E0, E1, E1);
    p[3] = make_float4(r, r, g, g);
    Pbb[n] = make_float2(b, b);
}

__global__ __launch_bounds__(TPB, 8) void splat_kernel(
    const float2* __restrict__ x, const float4* __restrict__ Pmain,
    const float2* __restrict__ Pbb, float* __restrict__ out)
{
    __shared__ float4 sm[GPB * 4];   // 8 KiB
    __shared__ float2 sb[GPB];       // 1 KiB

    // slice in HIGH bits: all 16 slices of a pg are 32-apart in blockIdx
    // -> same XCD under %8 round-robin -> atomic lines stay in one L2.
    const int pg    = blockIdx.x & (NPG - 1);
    const int slice = blockIdx.x >> 5;
    const int tid   = threadIdx.x;

    // stage this block's 128-gaussian slice once (coalesced float4)
    if (tid < GPB * 4) sm[tid] = Pmain[slice * (GPB * 4) + tid];
    if (tid < GPB)     sb[tid] = Pbb[slice * GPB + tid];

    const int p0 = pg * PPB + tid;        // pixel 0 (lane-coalesced)
    const int p1 = p0 + TPB;              // pixel 1
    float2 xy0 = x[p0];
    float2 xy1 = x[p1];
    v2f PX = {xy0.x - 0.5f * WID, xy1.x - 0.5f * WID};
    v2f PY = {xy0.y - 0.5f * HEI, xy1.y - 0.5f * HEI};

    __syncthreads();

    v2f ar = {0.f, 0.f}, ag = {0.f, 0.f}, ab = {0.f, 0.f};
    #pragma unroll 2
    for (int j = 0; j < GPB; ++j) {
        float4 c0 = sm[4*j + 0];   // A,A,B,B
        float4 c1 = sm[4*j + 1];   // C,C,D,D
        float4 c2 = sm[4*j + 2];   // E0,E0,E1,E1
        float4 c3 = sm[4*j + 3];   // r,r,g,g
        float2 cb = sb[j];
        v2f dx = __builtin_elementwise_fma(lo2(c0), PX,
                   __builtin_elementwise_fma(hi2(c0), PY, lo2(c2)));
        v2f dy = __builtin_elementwise_fma(lo2(c1), PX,
                   __builtin_elementwise_fma(hi2(c1), PY, hi2(c2)));
        v2f q  = __builtin_elementwise_fma(dx, dx, dy * dy);
        v2f w;
        w.x = __builtin_amdgcn_exp2f(-q.x);
        w.y = __builtin_amdgcn_exp2f(-q.y);
        ar = __builtin_elementwise_fma(w, lo2(c3), ar);
        ag = __builtin_elementwise_fma(w, hi2(c3), ag);
        ab = __builtin_elementwise_fma(w, (v2f){cb.x, cb.y}, ab);
    }

    atomicAdd(&out[3*p0 + 0], ar.x);
    atomicAdd(&out[3*p0 + 1], ag.x);
    atomicAdd(&out[3*p0 + 2], ab.x);
    atomicAdd(&out[3*p1 + 0], ar.y);
    atomicAdd(&out[3*p1 + 1], ag.y);
    atomicAdd(&out[3*p1 + 2], ab.y);
}

extern "C" void kernel_launch(void* const* d_in, const int* in_sizes, int n_in,
                              void* d_out, int out_size, void* d_ws, size_t ws_size,
                              hipStream_t stream) {
    const float* x     = (const float*)d_in[0];  // [B,2]
    const float* rgb   = (const float*)d_in[1];  // [N,3]
    const float* mu    = (const float*)d_in[2];  // [N,2]
    const float* scale = (const float*)d_in[3];  // [N,2]
    const float* angle = (const float*)d_in[4];  // [N]

    float4* Pmain = (float4*)d_ws;                         // 128 KiB
    float2* Pbb   = (float2*)((char*)d_ws + NGAUSS * 64);  // +16 KiB = 144 KiB

    hipMemsetAsync(d_out, 0, (size_t)out_size * sizeof(float), stream);

    hipLaunchKernelGGL(prep_kernel, dim3(NGAUSS / 256), dim3(256), 0, stream,
                       rgb, mu, scale, angle, Pmain, Pbb);
    hipLaunchKernelGGL(splat_kernel, dim3(NSLICE * NPG), dim3(TPB), 0, stream,
                       (const float2*)x, Pmain, Pbb, (float*)d_out);
}